// Round 1
// baseline (300.152 us; speedup 1.0000x reference)
//
#include <hip/hip_runtime.h>
#include <hip/hip_bf16.h>
#include <cstdint>

#define DEVI __device__ __forceinline__

typedef unsigned short u16;
typedef unsigned int u32;
typedef __attribute__((ext_vector_type(8))) short bf16x8;
typedef __attribute__((ext_vector_type(4))) float f32x4;

DEVI u16 f2bf(float f) {
    union { float f; u32 u; } v; v.f = f;
    u32 r = v.u + 0x7fffu + ((v.u >> 16) & 1u);
    return (u16)(r >> 16);
}
DEVI u32 pk2(float a, float b) { return (u32)f2bf(a) | ((u32)f2bf(b) << 16); }

DEVI void gload_lds16(const void* g, void* l) {
    __builtin_amdgcn_global_load_lds(
        (const __attribute__((address_space(1))) u32*)(uintptr_t)g,
        (__attribute__((address_space(3))) u32*)(u32)(uintptr_t)l,
        16, 0, 0);
}

// ---------------- prep kernels ----------------

// build bf16 ctx buffer [4][4608][512]: rows 0..511 <- x[b], 512..4607 <- context[b]
__global__ __launch_bounds__(256) void build_ctxb(const float* __restrict__ x,
                                                  const float* __restrict__ ctx,
                                                  u16* __restrict__ out) {
    int idx = blockIdx.x * 256 + threadIdx.x;          // one thread per 8 elems
    long e0 = (long)idx * 8;
    int b = (int)(e0 / (4608L * 512));
    long rem = e0 % (4608L * 512);
    int m = (int)(rem / 512);
    int d = (int)(rem % 512);
    const float* src = (m < 512) ? (x + ((long)b * 512 + m) * 512 + d)
                                 : (ctx + ((long)b * 4096 + (m - 512)) * 512 + d);
    float4 a = *(const float4*)src;
    float4 c = *(const float4*)(src + 4);
    uint4 u;
    u.x = pk2(a.x, a.y); u.y = pk2(a.z, a.w);
    u.z = pk2(c.x, c.y); u.w = pk2(c.z, c.w);
    *(uint4*)&out[e0] = u;
}

__global__ __launch_bounds__(256) void cast_bf16(const float* __restrict__ s,
                                                 u16* __restrict__ d) {
    int i = blockIdx.x * 256 + threadIdx.x;            // one thread per 8 elems
    const float4* s4 = (const float4*)s;
    float4 a = s4[i * 2], b = s4[i * 2 + 1];
    uint4 u;
    u.x = pk2(a.x, a.y); u.y = pk2(a.z, a.w);
    u.z = pk2(b.x, b.y); u.w = pk2(b.z, b.w);
    ((uint4*)d)[i] = u;
}

// ---------------- GEMM: C[M,N] = A[M,K] @ B[N,K]^T, K=512, bf16 in, CT out ----------------
// 128x128 tile, BK=64, 4 waves (2x2), each wave 64x64 via 4x4 16x16x32 MFMA frags.
// LDS layout: [row][64] with per-row chunk XOR-swizzle (chunk ^= row&7), staged via
// global_load_lds with pre-swizzled per-lane global source.
template <typename CT>
__global__ __launch_bounds__(256) void gemm_bt(const u16* __restrict__ A,
                                               const u16* __restrict__ B,
                                               CT* __restrict__ C,
                                               int N, int rpb, long bstride) {
    const int K = 512;
    __shared__ u16 Asm[128 * 64];
    __shared__ u16 Bsm[128 * 64];
    int tid = threadIdx.x;
    int w = tid >> 6, l = tid & 63;
    int g = l >> 4, c = l & 15;
    int wr = w >> 1, wc = w & 1;
    long r0 = (long)blockIdx.y * 128;
    long arow0 = (r0 / rpb) * bstride + (r0 % rpb) * K;
    int n0 = blockIdx.x * 128;

    f32x4 acc[4][4];
#pragma unroll
    for (int i = 0; i < 4; i++)
#pragma unroll
        for (int j = 0; j < 4; j++) acc[i][j] = (f32x4){0.f, 0.f, 0.f, 0.f};

    int srow = l >> 3;   // lane's row within an 8-row chunk-block
    int sch = l & 7;     // lane's 16B chunk within a 128B row

    for (int kt = 0; kt < 8; ++kt) {
#pragma unroll
        for (int i = 0; i < 4; i++) {
            int c2 = w * 4 + i;                 // 1KB chunk id, 0..15
            int row = c2 * 8 + srow;            // tile row 0..127
            int sc = sch ^ (row & 7);           // pre-swizzled source chunk
            gload_lds16(A + arow0 + (long)row * K + kt * 64 + sc * 8,
                        &Asm[c2 * 512 + (l << 3)]);
            gload_lds16(B + (long)(n0 + row) * K + kt * 64 + sc * 8,
                        &Bsm[c2 * 512 + (l << 3)]);
        }
        __syncthreads();
#pragma unroll
        for (int ks = 0; ks < 2; ++ks) {
            bf16x8 af[4], bfr[4];
#pragma unroll
            for (int mt = 0; mt < 4; ++mt) {
                int row = wr * 64 + mt * 16 + c;
                int ch = (ks * 4 + g) ^ (row & 7);
                af[mt] = *(const bf16x8*)&Asm[row * 64 + ch * 8];
            }
#pragma unroll
            for (int nt = 0; nt < 4; ++nt) {
                int row = wc * 64 + nt * 16 + c;
                int ch = (ks * 4 + g) ^ (row & 7);
                bfr[nt] = *(const bf16x8*)&Bsm[row * 64 + ch * 8];
            }
#pragma unroll
            for (int mt = 0; mt < 4; ++mt)
#pragma unroll
                for (int nt = 0; nt < 4; ++nt)
                    acc[mt][nt] = __builtin_amdgcn_mfma_f32_16x16x32_bf16(
                        af[mt], bfr[nt], acc[mt][nt], 0, 0, 0);
        }
        __syncthreads();
    }
#pragma unroll
    for (int mt = 0; mt < 4; ++mt) {
#pragma unroll
        for (int r = 0; r < 4; ++r) {
            long row = r0 + wr * 64 + mt * 16 + g * 4 + r;
#pragma unroll
            for (int nt = 0; nt < 4; ++nt) {
                int col = n0 + wc * 64 + nt * 16 + c;
                float v = acc[mt][nt][r];
                if constexpr (sizeof(CT) == 2) {
                    C[row * N + col] = (CT)f2bf(v);
                } else {
                    C[row * N + col] = v;
                }
            }
        }
    }
}

// ---------------- transpose V: kv[b,m,512+h*64+d] -> vT[b,h,d,m] ----------------
__global__ __launch_bounds__(256) void transpose_v(const u16* __restrict__ KV,
                                                   u16* __restrict__ VT) {
    __shared__ u16 T[64][72];
    int m0 = blockIdx.x * 64;
    int h = blockIdx.y, b = blockIdx.z;
    int tid = threadIdx.x;
    const long base = (long)b * 4608 * 1024 + 512 + h * 64;
#pragma unroll
    for (int j = 0; j < 2; j++) {
        int lin = tid + j * 256;
        int row = lin >> 3, chn = lin & 7;
        bf16x8 v = *(const bf16x8*)&KV[base + (long)(m0 + row) * 1024 + chn * 8];
#pragma unroll
        for (int e = 0; e < 8; e++) T[row][chn * 8 + e] = (u16)v[e];
    }
    __syncthreads();
    const long obase = (long)(b * 8 + h) * 64 * 4608 + m0;
#pragma unroll
    for (int j = 0; j < 2; j++) {
        int lin = tid + j * 256;
        int drow = lin >> 3, chn = lin & 7;
        bf16x8 v;
#pragma unroll
        for (int e = 0; e < 8; e++) v[e] = (short)T[chn * 8 + e][drow];
        *(bf16x8*)&VT[obase + (long)drow * 4608 + chn * 8] = v;
    }
}

// ---------------- flash attention ----------------
// grid (8 qblocks, 8 heads, 4 batch), 4 waves; wave owns 16 q rows, full d=64.
// K-tile/V^T-tile = 64 positions staged in swizzled LDS; P through wave-private LDS.
__global__ __launch_bounds__(256) void attn_kern(const u16* __restrict__ Q,
                                                 const u16* __restrict__ KV,
                                                 const u16* __restrict__ VT,
                                                 u16* __restrict__ O) {
    __shared__ u16 Ksm[64 * 64];
    __shared__ u16 Vsm[64 * 64];
    __shared__ u16 Psm[4 * 16 * 64];
    int tid = threadIdx.x;
    int w = tid >> 6, l = tid & 63;
    int g = l >> 4, c = l & 15;
    int qb0 = blockIdx.x * 64;
    int h = blockIdx.y, b = blockIdx.z;

    bf16x8 qf[2];
    {
        long qrow = (long)(b * 512 + qb0 + w * 16 + c);
#pragma unroll
        for (int ks = 0; ks < 2; ++ks)
            qf[ks] = *(const bf16x8*)&Q[qrow * 512 + h * 64 + ks * 32 + g * 8];
    }
    f32x4 o[4];
#pragma unroll
    for (int nt = 0; nt < 4; nt++) o[nt] = (f32x4){0.f, 0.f, 0.f, 0.f};
    float mrun[4], lrun[4];
#pragma unroll
    for (int r = 0; r < 4; r++) { mrun[r] = -1e30f; lrun[r] = 0.f; }

    const float SCL = 0.125f * 1.44269504f;  // 1/sqrt(64) * log2(e)
    int srow8 = l >> 3, sch = l & 7;
    const long kvbase = (long)b * 4608 * 1024 + h * 64;
    const long vtbase = (long)(b * 8 + h) * 64 * 4608;
    u16* Pw = &Psm[w * 16 * 64];

    for (int it = 0; it < 72; ++it) {
        __syncthreads();  // previous iter's LDS reads done before restage
#pragma unroll
        for (int i = 0; i < 2; i++) {
            int c2 = w * 2 + i;
            int row = c2 * 8 + srow8;
            int sc = sch ^ (row & 7);
            gload_lds16(KV + kvbase + (long)(it * 64 + row) * 1024 + sc * 8,
                        &Ksm[c2 * 512 + (l << 3)]);
            gload_lds16(VT + vtbase + (long)row * 4608 + it * 64 + sc * 8,
                        &Vsm[c2 * 512 + (l << 3)]);
        }
        __syncthreads();

        // S = Q @ K^T : S[q=g*4+r][kb=c+16t]
        f32x4 s[4];
#pragma unroll
        for (int t = 0; t < 4; t++) s[t] = (f32x4){0.f, 0.f, 0.f, 0.f};
#pragma unroll
        for (int ks = 0; ks < 2; ++ks) {
#pragma unroll
            for (int t = 0; t < 4; t++) {
                int row = t * 16 + c;
                int ch = (ks * 4 + g) ^ (row & 7);
                bf16x8 kf = *(const bf16x8*)&Ksm[row * 64 + ch * 8];
                s[t] = __builtin_amdgcn_mfma_f32_16x16x32_bf16(qf[ks], kf, s[t], 0, 0, 0);
            }
        }
        // online softmax (exp2 domain)
        float mnew[4], rf[4];
#pragma unroll
        for (int r = 0; r < 4; r++) {
            float mx = fmaxf(fmaxf(s[0][r], s[1][r]), fmaxf(s[2][r], s[3][r]));
            mx *= SCL;
#pragma unroll
            for (int off = 1; off < 16; off <<= 1) mx = fmaxf(mx, __shfl_xor(mx, off));
            mnew[r] = fmaxf(mrun[r], mx);
            rf[r] = exp2f(mrun[r] - mnew[r]);
            mrun[r] = mnew[r];
        }
#pragma unroll
        for (int t = 0; t < 4; t++)
#pragma unroll
            for (int r = 0; r < 4; r++) s[t][r] = exp2f(s[t][r] * SCL - mnew[r]);
#pragma unroll
        for (int r = 0; r < 4; r++) {
            float su = s[0][r] + s[1][r] + s[2][r] + s[3][r];
#pragma unroll
            for (int off = 1; off < 16; off <<= 1) su += __shfl_xor(su, off);
            lrun[r] = lrun[r] * rf[r] + su;
        }
#pragma unroll
        for (int nt = 0; nt < 4; nt++)
#pragma unroll
            for (int r = 0; r < 4; r++) o[nt][r] *= rf[r];
        // P -> wave-private swizzled LDS
#pragma unroll
        for (int t = 0; t < 4; t++) {
            int colc = c + t * 16;
            int chunk = colc >> 3;
#pragma unroll
            for (int r = 0; r < 4; r++) {
                int row = g * 4 + r;
                Pw[row * 64 + ((chunk ^ (row & 7)) << 3) + (colc & 7)] = f2bf(s[t][r]);
            }
        }
        // O += P @ V
#pragma unroll
        for (int ks = 0; ks < 2; ++ks) {
            int pch = (ks * 4 + g) ^ (c & 7);
            bf16x8 pa = *(const bf16x8*)&Pw[c * 64 + pch * 8];
#pragma unroll
            for (int nt = 0; nt < 4; nt++) {
                int vrow = nt * 16 + c;
                int vch = (ks * 4 + g) ^ (vrow & 7);
                bf16x8 vb = *(const bf16x8*)&Vsm[vrow * 64 + vch * 8];
                o[nt] = __builtin_amdgcn_mfma_f32_16x16x32_bf16(pa, vb, o[nt], 0, 0, 0);
            }
        }
    }
#pragma unroll
    for (int r = 0; r < 4; r++) {
        float inv = 1.0f / lrun[r];
        long row = (long)(b * 512 + qb0 + w * 16 + g * 4 + r);
#pragma unroll
        for (int nt = 0; nt < 4; nt++)
            O[row * 512 + h * 64 + nt * 16 + c] = f2bf(o[nt][r] * inv);
    }
}

// ---------------- launch ----------------

extern "C" void kernel_launch(void* const* d_in, const int* in_sizes, int n_in,
                              void* d_out, int out_size, void* d_ws, size_t ws_size,
                              hipStream_t stream) {
    const float* x = (const float*)d_in[0];
    const float* ctx = (const float*)d_in[1];
    const float* Wq = (const float*)d_in[2];
    const float* Wkv = (const float*)d_in[3];
    const float* Wout = (const float*)d_in[4];
    float* out = (float*)d_out;

    char* ws = (char*)d_ws;
    size_t off = 0;
    auto alloc = [&](size_t bytes) {
        size_t r = off;
        off += (bytes + 255) & ~(size_t)255;
        return r;
    };
    u16* ctxb = (u16*)(ws + alloc(4L * 4608 * 512 * 2));       // 18.9 MB
    u16* wqb = (u16*)(ws + alloc(512L * 512 * 2));
    u16* wkvb = (u16*)(ws + alloc(1024L * 512 * 2));
    u16* woutb = (u16*)(ws + alloc(512L * 512 * 2));
    u16* qb = (u16*)(ws + alloc(2048L * 512 * 2));
    u16* kvb = (u16*)(ws + alloc(18432L * 1024 * 2));          // 37.7 MB
    u16* vtb = (u16*)(ws + alloc(4L * 8 * 64 * 4608 * 2));     // 18.9 MB
    u16* aob = (u16*)(ws + alloc(2048L * 512 * 2));

    build_ctxb<<<dim3(4608), dim3(256), 0, stream>>>(x, ctx, ctxb);
    cast_bf16<<<dim3(128), dim3(256), 0, stream>>>(Wq, wqb);
    cast_bf16<<<dim3(256), dim3(256), 0, stream>>>(Wkv, wkvb);
    cast_bf16<<<dim3(128), dim3(256), 0, stream>>>(Wout, woutb);

    // q projection: M=2048, N=512; A rows map to ctxb batch-prefixed rows
    gemm_bt<u16><<<dim3(4, 16), dim3(256), 0, stream>>>(ctxb, wqb, qb, 512, 512,
                                                        (long)4608 * 512);
    // kv projection: M=18432, N=1024
    gemm_bt<u16><<<dim3(8, 144), dim3(256), 0, stream>>>(ctxb, wkvb, kvb, 1024, 4608,
                                                         (long)4608 * 512);
    transpose_v<<<dim3(72, 8, 4), dim3(256), 0, stream>>>(kvb, vtb);
    attn_kern<<<dim3(8, 8, 4), dim3(256), 0, stream>>>(qb, kvb, vtb, aob);
    // out projection: M=2048, N=512 -> f32
    gemm_bt<float><<<dim3(4, 16), dim3(256), 0, stream>>>(aob, woutb, out, 512, 2048,
                                                          (long)2048 * 512);
}

// Round 2
// 257.134 us; speedup vs baseline: 1.1673x; 1.1673x over previous
//
#include <hip/hip_runtime.h>
#include <hip/hip_bf16.h>
#include <cstdint>

#define DEVI __device__ __forceinline__

typedef unsigned short u16;
typedef unsigned int u32;
typedef __attribute__((ext_vector_type(8))) short bf16x8;
typedef __attribute__((ext_vector_type(4))) float f32x4;

DEVI u16 f2bf(float f) {
    union { float f; u32 u; } v; v.f = f;
    u32 r = v.u + 0x7fffu + ((v.u >> 16) & 1u);
    return (u16)(r >> 16);
}
DEVI u32 pk2(float a, float b) { return (u32)f2bf(a) | ((u32)f2bf(b) << 16); }

DEVI void gload_lds16(const void* g, void* l) {
    __builtin_amdgcn_global_load_lds(
        (const __attribute__((address_space(1))) u32*)(uintptr_t)g,
        (__attribute__((address_space(3))) u32*)(u32)(uintptr_t)l,
        16, 0, 0);
}

// ---------------- prep kernels ----------------

// build bf16 ctx buffer [4][4608][512]: rows 0..511 <- x[b], 512..4607 <- context[b]
__global__ __launch_bounds__(256) void build_ctxb(const float* __restrict__ x,
                                                  const float* __restrict__ ctx,
                                                  u16* __restrict__ out) {
    int idx = blockIdx.x * 256 + threadIdx.x;          // one thread per 8 elems
    long e0 = (long)idx * 8;
    int b = (int)(e0 / (4608L * 512));
    long rem = e0 % (4608L * 512);
    int m = (int)(rem / 512);
    int d = (int)(rem % 512);
    const float* src = (m < 512) ? (x + ((long)b * 512 + m) * 512 + d)
                                 : (ctx + ((long)b * 4096 + (m - 512)) * 512 + d);
    float4 a = *(const float4*)src;
    float4 c = *(const float4*)(src + 4);
    uint4 u;
    u.x = pk2(a.x, a.y); u.y = pk2(a.z, a.w);
    u.z = pk2(c.x, c.y); u.w = pk2(c.z, c.w);
    *(uint4*)&out[e0] = u;
}

__global__ __launch_bounds__(256) void cast_bf16(const float* __restrict__ s,
                                                 u16* __restrict__ d) {
    int i = blockIdx.x * 256 + threadIdx.x;            // one thread per 8 elems
    const float4* s4 = (const float4*)s;
    float4 a = s4[i * 2], b = s4[i * 2 + 1];
    uint4 u;
    u.x = pk2(a.x, a.y); u.y = pk2(a.z, a.w);
    u.z = pk2(b.x, b.y); u.w = pk2(b.z, b.w);
    ((uint4*)d)[i] = u;
}

// ---------------- GEMM: C[M,N] = A[M,K] @ B[N,K]^T, K=512, bf16 in ----------------
// 128x128 tile, BK=64, 4 waves (2x2), 2-phase double-buffered staging via
// global_load_lds (width 16) with pre-swizzled source + swizzled ds_read_b128.
// SPLITV: N-tiles >=512 are the V half of the kv projection, written directly
// transposed to VT[b,h,d,m]; K half written to C with stride 512.
template <typename CT, bool SPLITV>
__global__ __launch_bounds__(256) void gemm_bt(const u16* __restrict__ A,
                                               const u16* __restrict__ B,
                                               CT* __restrict__ C,
                                               u16* __restrict__ VT,
                                               int N, int rpb, long bstride) {
    const int K = 512;
    __shared__ u16 Asm[2][128 * 64];
    __shared__ u16 Bsm[2][128 * 64];
    int tid = threadIdx.x;
    int w = tid >> 6, l = tid & 63;
    int g = l >> 4, c = l & 15;
    int wr = w >> 1, wc = w & 1;
    long r0 = (long)blockIdx.y * 128;
    long arow0 = (r0 / rpb) * bstride + (r0 % rpb) * K;
    int n0 = blockIdx.x * 128;

    f32x4 acc[4][4];
#pragma unroll
    for (int i = 0; i < 4; i++)
#pragma unroll
        for (int j = 0; j < 4; j++) acc[i][j] = (f32x4){0.f, 0.f, 0.f, 0.f};

    int srow = l >> 3;   // lane's row within an 8-row chunk-block
    int sch = l & 7;     // lane's 16B chunk within a 128B row

    auto stage = [&](int kt, int bb) {
#pragma unroll
        for (int i = 0; i < 4; i++) {
            int c2 = w * 4 + i;                 // 1KB chunk id, 0..15
            int row = c2 * 8 + srow;            // tile row 0..127
            int sc = sch ^ (row & 7);           // pre-swizzled source chunk
            gload_lds16(A + arow0 + (long)row * K + kt * 64 + sc * 8,
                        &Asm[bb][c2 * 512 + (l << 3)]);
            gload_lds16(B + (long)(n0 + row) * K + kt * 64 + sc * 8,
                        &Bsm[bb][c2 * 512 + (l << 3)]);
        }
    };

    stage(0, 0);
    __syncthreads();
    for (int kt0 = 0; kt0 < 8; kt0 += 2) {
#pragma unroll
        for (int jj = 0; jj < 2; ++jj) {
            int kt = kt0 + jj;
            if (kt < 7) stage(kt + 1, jj ^ 1);  // prefetch overlaps compute
#pragma unroll
            for (int ks = 0; ks < 2; ++ks) {
                bf16x8 af[4], bfr[4];
#pragma unroll
                for (int mt = 0; mt < 4; ++mt) {
                    int row = wr * 64 + mt * 16 + c;
                    int ch = (ks * 4 + g) ^ (row & 7);
                    af[mt] = *(const bf16x8*)&Asm[jj][row * 64 + ch * 8];
                }
#pragma unroll
                for (int nt = 0; nt < 4; ++nt) {
                    int row = wc * 64 + nt * 16 + c;
                    int ch = (ks * 4 + g) ^ (row & 7);
                    bfr[nt] = *(const bf16x8*)&Bsm[jj][row * 64 + ch * 8];
                }
#pragma unroll
                for (int mt = 0; mt < 4; ++mt)
#pragma unroll
                    for (int nt = 0; nt < 4; ++nt)
                        acc[mt][nt] = __builtin_amdgcn_mfma_f32_16x16x32_bf16(
                            af[mt], bfr[nt], acc[mt][nt], 0, 0, 0);
            }
            __syncthreads();   // drains prefetch vmcnt; guards buffer reuse
        }
    }

    if constexpr (SPLITV) {
        if (n0 >= 512) {     // V tile -> write transposed VT[b,h,d,m]
            int b2 = (int)(r0 / rpb);
            int mb = (int)(r0 - (long)b2 * rpb) + wr * 64;
#pragma unroll
            for (int mt = 0; mt < 4; ++mt) {
#pragma unroll
                for (int nt = 0; nt < 4; ++nt) {
                    int colv = (n0 - 512) + wc * 64 + nt * 16 + c;
                    int hh = colv >> 6, dd = colv & 63;
                    long ob = ((long)(b2 * 8 + hh) * 64 + dd) * 4608 + mb + mt * 16 + g * 4;
                    ushort4 pk;
                    pk.x = f2bf(acc[mt][nt][0]);
                    pk.y = f2bf(acc[mt][nt][1]);
                    pk.z = f2bf(acc[mt][nt][2]);
                    pk.w = f2bf(acc[mt][nt][3]);
                    *(ushort4*)&VT[ob] = pk;
                }
            }
            return;
        }
    }
#pragma unroll
    for (int mt = 0; mt < 4; ++mt) {
#pragma unroll
        for (int r = 0; r < 4; ++r) {
            long row = r0 + wr * 64 + mt * 16 + g * 4 + r;
#pragma unroll
            for (int nt = 0; nt < 4; ++nt) {
                int col = n0 + wc * 64 + nt * 16 + c;
                float v = acc[mt][nt][r];
                if constexpr (sizeof(CT) == 2) {
                    C[row * (long)N + col] = (CT)f2bf(v);
                } else {
                    C[row * (long)N + col] = v;
                }
            }
        }
    }
}

// ---------------- flash attention ----------------
// 256 blocks (XCD-remapped so 8 qblocks sharing one (b,h) KV panel co-locate on
// one XCD), 4 waves; wave owns 16 q rows, d=64. Depth-2 pipelined K/V staging:
// 3-buffer rotation, counted s_waitcnt vmcnt(4), single raw s_barrier per iter.
__global__ __launch_bounds__(256) void attn_kern(const u16* __restrict__ Q,
                                                 const u16* __restrict__ KB,
                                                 const u16* __restrict__ VT,
                                                 u16* __restrict__ O) {
    __shared__ u16 Ksm[3][64 * 64];
    __shared__ u16 Vsm[3][64 * 64];
    __shared__ u16 Psm[4 * 16 * 64];
    int tid = threadIdx.x;
    int w = tid >> 6, l = tid & 63;
    int g = l >> 4, c = l & 15;
    // XCD remap: assume round-robin id%8 -> XCD; give each XCD 4 (b,h) pairs
    int id = blockIdx.x;
    int slot = id >> 3;
    int p = (id & 7) * 4 + (slot >> 3);   // (b,h) pair 0..31
    int qb0 = (slot & 7) * 64;
    int b = p >> 3, h = p & 7;

    bf16x8 qf[2];
    {
        long qrow = (long)(b * 512 + qb0 + w * 16 + c);
#pragma unroll
        for (int ks = 0; ks < 2; ++ks)
            qf[ks] = *(const bf16x8*)&Q[qrow * 512 + h * 64 + ks * 32 + g * 8];
    }
    f32x4 o[4];
#pragma unroll
    for (int nt = 0; nt < 4; nt++) o[nt] = (f32x4){0.f, 0.f, 0.f, 0.f};
    float mrun[4], lrun[4];
#pragma unroll
    for (int r = 0; r < 4; r++) { mrun[r] = -1e30f; lrun[r] = 0.f; }

    const float SCL = 0.125f * 1.44269504f;  // 1/sqrt(64) * log2(e)
    int srow8 = l >> 3, sch = l & 7;
    const long kbase = (long)b * 4608 * 512 + h * 64;
    const long vtbase = (long)(b * 8 + h) * 64 * 4608;
    u16* Pw = &Psm[w * 16 * 64];

    auto stage = [&](int it, int bb) {
#pragma unroll
        for (int i = 0; i < 2; i++) {
            int c2 = w * 2 + i;
            int row = c2 * 8 + srow8;
            int sc = sch ^ (row & 7);
            gload_lds16(KB + kbase + (long)(it * 64 + row) * 512 + sc * 8,
                        &Ksm[bb][c2 * 512 + (l << 3)]);
            gload_lds16(VT + vtbase + (long)row * 4608 + it * 64 + sc * 8,
                        &Vsm[bb][c2 * 512 + (l << 3)]);
        }
    };

    stage(0, 0);
    stage(1, 1);

    for (int base = 0; base < 72; base += 3) {
#pragma unroll
        for (int j = 0; j < 3; ++j) {
            int it = base + j;
            // tile `it` = oldest 4 outstanding loads; tile it+1 stays in flight
            if (it < 71) asm volatile("s_waitcnt vmcnt(4)" ::: "memory");
            else         asm volatile("s_waitcnt vmcnt(0)" ::: "memory");
            __builtin_amdgcn_s_barrier();
            __builtin_amdgcn_sched_barrier(0);
            if (it < 70) stage(it + 2, (j + 2) % 3);   // prefetch 2 ahead

            // S = Q @ K^T : S[q=g*4+r][kb=c+16t]
            f32x4 s[4];
#pragma unroll
            for (int t = 0; t < 4; t++) s[t] = (f32x4){0.f, 0.f, 0.f, 0.f};
#pragma unroll
            for (int ks = 0; ks < 2; ++ks) {
#pragma unroll
                for (int t = 0; t < 4; t++) {
                    int row = t * 16 + c;
                    int ch = (ks * 4 + g) ^ (row & 7);
                    bf16x8 kf = *(const bf16x8*)&Ksm[j][row * 64 + ch * 8];
                    s[t] = __builtin_amdgcn_mfma_f32_16x16x32_bf16(qf[ks], kf, s[t], 0, 0, 0);
                }
            }
            // online softmax (exp2 domain)
            float mnew[4], rf[4];
#pragma unroll
            for (int r = 0; r < 4; r++) {
                float mx = fmaxf(fmaxf(s[0][r], s[1][r]), fmaxf(s[2][r], s[3][r]));
                mx *= SCL;
#pragma unroll
                for (int off = 1; off < 16; off <<= 1) mx = fmaxf(mx, __shfl_xor(mx, off));
                mnew[r] = fmaxf(mrun[r], mx);
                rf[r] = exp2f(mrun[r] - mnew[r]);
                mrun[r] = mnew[r];
            }
#pragma unroll
            for (int t = 0; t < 4; t++)
#pragma unroll
                for (int r = 0; r < 4; r++) s[t][r] = exp2f(s[t][r] * SCL - mnew[r]);
#pragma unroll
            for (int r = 0; r < 4; r++) {
                float su = s[0][r] + s[1][r] + s[2][r] + s[3][r];
#pragma unroll
                for (int off = 1; off < 16; off <<= 1) su += __shfl_xor(su, off);
                lrun[r] = lrun[r] * rf[r] + su;
            }
#pragma unroll
            for (int nt = 0; nt < 4; nt++)
#pragma unroll
                for (int r = 0; r < 4; r++) o[nt][r] *= rf[r];
            // P -> wave-private swizzled LDS
#pragma unroll
            for (int t = 0; t < 4; t++) {
                int colc = c + t * 16;
                int chunk = colc >> 3;
#pragma unroll
                for (int r = 0; r < 4; r++) {
                    int row = g * 4 + r;
                    Pw[row * 64 + ((chunk ^ (row & 7)) << 3) + (colc & 7)] = f2bf(s[t][r]);
                }
            }
            // O += P @ V
#pragma unroll
            for (int ks = 0; ks < 2; ++ks) {
                int pch = (ks * 4 + g) ^ (c & 7);
                bf16x8 pa = *(const bf16x8*)&Pw[c * 64 + pch * 8];
#pragma unroll
                for (int nt = 0; nt < 4; nt++) {
                    int vrow = nt * 16 + c;
                    int vch = (ks * 4 + g) ^ (vrow & 7);
                    bf16x8 vb = *(const bf16x8*)&Vsm[j][vrow * 64 + vch * 8];
                    o[nt] = __builtin_amdgcn_mfma_f32_16x16x32_bf16(pa, vb, o[nt], 0, 0, 0);
                }
            }
        }
    }
#pragma unroll
    for (int r = 0; r < 4; r++) {
        float inv = 1.0f / lrun[r];
        long row = (long)(b * 512 + qb0 + w * 16 + g * 4 + r);
#pragma unroll
        for (int nt = 0; nt < 4; nt++)
            O[row * 512 + h * 64 + nt * 16 + c] = f2bf(o[nt][r] * inv);
    }
}

// ---------------- launch ----------------

extern "C" void kernel_launch(void* const* d_in, const int* in_sizes, int n_in,
                              void* d_out, int out_size, void* d_ws, size_t ws_size,
                              hipStream_t stream) {
    const float* x = (const float*)d_in[0];
    const float* ctx = (const float*)d_in[1];
    const float* Wq = (const float*)d_in[2];
    const float* Wkv = (const float*)d_in[3];
    const float* Wout = (const float*)d_in[4];
    float* out = (float*)d_out;

    char* ws = (char*)d_ws;
    size_t off = 0;
    auto alloc = [&](size_t bytes) {
        size_t r = off;
        off += (bytes + 255) & ~(size_t)255;
        return r;
    };
    u16* ctxb = (u16*)(ws + alloc(4L * 4608 * 512 * 2));       // 18.9 MB
    u16* wqb = (u16*)(ws + alloc(512L * 512 * 2));
    u16* wkvb = (u16*)(ws + alloc(1024L * 512 * 2));
    u16* woutb = (u16*)(ws + alloc(512L * 512 * 2));
    u16* qb = (u16*)(ws + alloc(2048L * 512 * 2));
    u16* kb = (u16*)(ws + alloc(4L * 4608 * 512 * 2));         // 18.9 MB (K only)
    u16* vtb = (u16*)(ws + alloc(4L * 8 * 64 * 4608 * 2));     // 18.9 MB (V^T)
    u16* aob = (u16*)(ws + alloc(2048L * 512 * 2));

    build_ctxb<<<dim3(4608), dim3(256), 0, stream>>>(x, ctx, ctxb);
    cast_bf16<<<dim3(128), dim3(256), 0, stream>>>(Wq, wqb);
    cast_bf16<<<dim3(256), dim3(256), 0, stream>>>(Wkv, wkvb);
    cast_bf16<<<dim3(128), dim3(256), 0, stream>>>(Wout, woutb);

    // q projection: M=2048, N=512
    gemm_bt<u16, false><<<dim3(4, 16), dim3(256), 0, stream>>>(
        ctxb, wqb, qb, nullptr, 512, 512, (long)4608 * 512);
    // kv projection: M=18432, N=1024; K half -> kb (stride 512), V half -> vtb transposed
    gemm_bt<u16, true><<<dim3(8, 144), dim3(256), 0, stream>>>(
        ctxb, wkvb, kb, vtb, 512, 4608, (long)4608 * 512);
    attn_kern<<<dim3(256), dim3(256), 0, stream>>>(qb, kb, vtb, aob);
    // out projection: M=2048, N=512 -> f32
    gemm_bt<float, false><<<dim3(4, 16), dim3(256), 0, stream>>>(
        aob, woutb, out, nullptr, 512, 2048, (long)2048 * 512);
}

// Round 3
// 212.719 us; speedup vs baseline: 1.4110x; 1.2088x over previous
//
#include <hip/hip_runtime.h>
#include <hip/hip_bf16.h>
#include <cstdint>

#define DEVI __device__ __forceinline__

typedef unsigned short u16;
typedef unsigned int u32;
typedef __attribute__((ext_vector_type(8))) short bf16x8;
typedef __attribute__((ext_vector_type(4))) float f32x4;

DEVI u16 f2bf(float f) {
    union { float f; u32 u; } v; v.f = f;
    u32 r = v.u + 0x7fffu + ((v.u >> 16) & 1u);
    return (u16)(r >> 16);
}
DEVI u32 pk2(float a, float b) { return (u32)f2bf(a) | ((u32)f2bf(b) << 16); }

DEVI void gload_lds16(const void* g, void* l) {
    __builtin_amdgcn_global_load_lds(
        (const __attribute__((address_space(1))) u32*)(uintptr_t)g,
        (__attribute__((address_space(3))) u32*)(u32)(uintptr_t)l,
        16, 0, 0);
}

// ---------------- prep kernels ----------------

__global__ __launch_bounds__(256) void build_ctxb(const float* __restrict__ x,
                                                  const float* __restrict__ ctx,
                                                  u16* __restrict__ out) {
    int idx = blockIdx.x * 256 + threadIdx.x;
    long e0 = (long)idx * 8;
    int b = (int)(e0 / (4608L * 512));
    long rem = e0 % (4608L * 512);
    int m = (int)(rem / 512);
    int d = (int)(rem % 512);
    const float* src = (m < 512) ? (x + ((long)b * 512 + m) * 512 + d)
                                 : (ctx + ((long)b * 4096 + (m - 512)) * 512 + d);
    float4 a = *(const float4*)src;
    float4 c = *(const float4*)(src + 4);
    uint4 u;
    u.x = pk2(a.x, a.y); u.y = pk2(a.z, a.w);
    u.z = pk2(c.x, c.y); u.w = pk2(c.z, c.w);
    *(uint4*)&out[e0] = u;
}

__global__ __launch_bounds__(256) void cast_bf16(const float* __restrict__ s,
                                                 u16* __restrict__ d) {
    int i = blockIdx.x * 256 + threadIdx.x;
    const float4* s4 = (const float4*)s;
    float4 a = s4[i * 2], b = s4[i * 2 + 1];
    uint4 u;
    u.x = pk2(a.x, a.y); u.y = pk2(a.z, a.w);
    u.z = pk2(b.x, b.y); u.w = pk2(b.z, b.w);
    ((uint4*)d)[i] = u;
}

// ---------------- GEMM: C[M,N] = A[M,K] @ B[N,K]^T, K=512, bf16 in ----------------
// 128x128 tile, BK=64, 4 waves (2x2). Double-buffered staging with COUNTED
// s_waitcnt vmcnt(8) (prefetch stays in flight across barriers) + raw barriers.
template <typename CT, bool SPLITV>
__global__ __launch_bounds__(256) void gemm_bt(const u16* __restrict__ A,
                                               const u16* __restrict__ B,
                                               CT* __restrict__ C,
                                               u16* __restrict__ VT,
                                               int N, int rpb, long bstride) {
    const int K = 512;
    __shared__ u16 Asm[2][128 * 64];
    __shared__ u16 Bsm[2][128 * 64];
    int tid = threadIdx.x;
    int w = tid >> 6, l = tid & 63;
    int g = l >> 4, c = l & 15;
    int wr = w >> 1, wc = w & 1;
    long r0 = (long)blockIdx.y * 128;
    long arow0 = (r0 / rpb) * bstride + (r0 % rpb) * K;
    int n0 = blockIdx.x * 128;

    f32x4 acc[4][4];
#pragma unroll
    for (int i = 0; i < 4; i++)
#pragma unroll
        for (int j = 0; j < 4; j++) acc[i][j] = (f32x4){0.f, 0.f, 0.f, 0.f};

    int srow = l >> 3;
    int sch = l & 7;

    auto stage = [&](int kt, int bb) {
#pragma unroll
        for (int i = 0; i < 4; i++) {
            int c2 = w * 4 + i;
            int row = c2 * 8 + srow;
            int sc = sch ^ (row & 7);
            gload_lds16(A + arow0 + (long)row * K + kt * 64 + sc * 8,
                        &Asm[bb][c2 * 512 + (l << 3)]);
            gload_lds16(B + (long)(n0 + row) * K + kt * 64 + sc * 8,
                        &Bsm[bb][c2 * 512 + (l << 3)]);
        }
    };

    stage(0, 0);
#pragma unroll 2
    for (int kt = 0; kt < 8; ++kt) {
        int pb = kt & 1;
        if (kt < 7) {
            stage(kt + 1, pb ^ 1);
            asm volatile("s_waitcnt vmcnt(8)" ::: "memory");
        } else {
            asm volatile("s_waitcnt vmcnt(0)" ::: "memory");
        }
        __builtin_amdgcn_s_barrier();      // tile kt resident everywhere
        __builtin_amdgcn_sched_barrier(0);
#pragma unroll
        for (int ks = 0; ks < 2; ++ks) {
            bf16x8 af[4], bfr[4];
#pragma unroll
            for (int mt = 0; mt < 4; ++mt) {
                int row = wr * 64 + mt * 16 + c;
                int ch = (ks * 4 + g) ^ (row & 7);
                af[mt] = *(const bf16x8*)&Asm[pb][row * 64 + ch * 8];
            }
#pragma unroll
            for (int nt = 0; nt < 4; ++nt) {
                int row = wc * 64 + nt * 16 + c;
                int ch = (ks * 4 + g) ^ (row & 7);
                bfr[nt] = *(const bf16x8*)&Bsm[pb][row * 64 + ch * 8];
            }
#pragma unroll
            for (int mt = 0; mt < 4; ++mt)
#pragma unroll
                for (int nt = 0; nt < 4; ++nt)
                    acc[mt][nt] = __builtin_amdgcn_mfma_f32_16x16x32_bf16(
                        af[mt], bfr[nt], acc[mt][nt], 0, 0, 0);
        }
        __builtin_amdgcn_s_barrier();      // all waves done reading buf[pb]
    }

    if constexpr (SPLITV) {
        if (n0 >= 512) {
            int b2 = (int)(r0 / rpb);
            int mb = (int)(r0 - (long)b2 * rpb) + wr * 64;
#pragma unroll
            for (int mt = 0; mt < 4; ++mt) {
#pragma unroll
                for (int nt = 0; nt < 4; ++nt) {
                    int colv = (n0 - 512) + wc * 64 + nt * 16 + c;
                    int hh = colv >> 6, dd = colv & 63;
                    long ob = ((long)(b2 * 8 + hh) * 64 + dd) * 4608 + mb + mt * 16 + g * 4;
                    ushort4 pk;
                    pk.x = f2bf(acc[mt][nt][0]);
                    pk.y = f2bf(acc[mt][nt][1]);
                    pk.z = f2bf(acc[mt][nt][2]);
                    pk.w = f2bf(acc[mt][nt][3]);
                    *(ushort4*)&VT[ob] = pk;
                }
            }
            return;
        }
    }
#pragma unroll
    for (int mt = 0; mt < 4; ++mt) {
#pragma unroll
        for (int r = 0; r < 4; ++r) {
            long row = r0 + wr * 64 + mt * 16 + g * 4 + r;
#pragma unroll
            for (int nt = 0; nt < 4; ++nt) {
                int col = n0 + wc * 64 + nt * 16 + c;
                float v = acc[mt][nt][r];
                if constexpr (sizeof(CT) == 2) {
                    C[row * (long)N + col] = (CT)f2bf(v);
                } else {
                    C[row * (long)N + col] = v;
                }
            }
        }
    }
}

// ---------------- flash attention, split-KV x4 ----------------
// 1024 blocks: (b,h) x 4 kv-chunks x 8 qblocks, XCD-remapped so the 8 qblocks of
// one (b,h,chunk) share an XCD's L2. 4 waves/block, 40KB LDS -> 4 blocks/CU.
// Double-buffered K/V staging, counted vmcnt(4), two raw barriers/iter.
// Row-sums via ones-MFMA; defer-max (THR=8) skips rescale on most tiles.
// Writes unnormalized O partials + (m,l) per row; attn_combine merges.
__global__ __launch_bounds__(256) void attn_kern(const u16* __restrict__ Q,
                                                 const u16* __restrict__ KB,
                                                 const u16* __restrict__ VT,
                                                 float* __restrict__ Op,
                                                 float2* __restrict__ ML) {
    __shared__ u16 Ksm[2][64 * 64];
    __shared__ u16 Vsm[2][64 * 64];
    __shared__ u16 Psm[4 * 16 * 64];
    int tid = threadIdx.x;
    int w = tid >> 6, l = tid & 63;
    int g = l >> 4, c = l & 15;
    int id = blockIdx.x;
    int u = (id & 7) | ((id >> 6) << 3);   // unit (b,h,chunk) 0..127
    int qi = (id >> 3) & 7;
    int p_ = u >> 2, chunk = u & 3;
    int b = p_ >> 3, h = p_ & 7;
    int qb0 = qi * 64;
    const int NT = 18;
    int it0 = chunk * NT;

    bf16x8 qf[2];
    {
        long qrow = (long)(b * 512 + qb0 + w * 16 + c);
#pragma unroll
        for (int ks = 0; ks < 2; ++ks)
            qf[ks] = *(const bf16x8*)&Q[qrow * 512 + h * 64 + ks * 32 + g * 8];
    }
    bf16x8 onesf;
#pragma unroll
    for (int e = 0; e < 8; e++) onesf[e] = (short)0x3F80;  // bf16 1.0

    f32x4 o[4];
#pragma unroll
    for (int nt = 0; nt < 4; nt++) o[nt] = (f32x4){0.f, 0.f, 0.f, 0.f};
    f32x4 ls = (f32x4){0.f, 0.f, 0.f, 0.f};
    float mrun[4];
#pragma unroll
    for (int r = 0; r < 4; r++) mrun[r] = -1e30f;

    const float SCL = 0.125f * 1.44269504f;
    int srow8 = l >> 3, sch = l & 7;
    const long kbase = (long)b * 4608 * 512 + h * 64;
    const long vtbase = (long)(b * 8 + h) * 64 * 4608;
    u16* Pw = &Psm[w * 16 * 64];

    auto stage = [&](int it, int bb) {
#pragma unroll
        for (int i = 0; i < 2; i++) {
            int c2 = w * 2 + i;
            int row = c2 * 8 + srow8;
            int sc = sch ^ (row & 7);
            gload_lds16(KB + kbase + (long)(it * 64 + row) * 512 + sc * 8,
                        &Ksm[bb][c2 * 512 + (l << 3)]);
            gload_lds16(VT + vtbase + (long)row * 4608 + it * 64 + sc * 8,
                        &Vsm[bb][c2 * 512 + (l << 3)]);
        }
    };

    stage(it0, 0);
#pragma unroll 2
    for (int t = 0; t < NT; ++t) {
        int pbuf = t & 1;
        if (t + 1 < NT) {
            stage(it0 + t + 1, pbuf ^ 1);
            asm volatile("s_waitcnt vmcnt(4)" ::: "memory");
        } else {
            asm volatile("s_waitcnt vmcnt(0)" ::: "memory");
        }
        __builtin_amdgcn_s_barrier();      // tile t resident everywhere
        __builtin_amdgcn_sched_barrier(0);

        // S = Q @ K^T : S[q=g*4+r][kv=c+16t']
        f32x4 s[4];
#pragma unroll
        for (int t2 = 0; t2 < 4; t2++) s[t2] = (f32x4){0.f, 0.f, 0.f, 0.f};
#pragma unroll
        for (int ks = 0; ks < 2; ++ks) {
#pragma unroll
            for (int t2 = 0; t2 < 4; t2++) {
                int row = t2 * 16 + c;
                int ch = (ks * 4 + g) ^ (row & 7);
                bf16x8 kf = *(const bf16x8*)&Ksm[pbuf][row * 64 + ch * 8];
                s[t2] = __builtin_amdgcn_mfma_f32_16x16x32_bf16(qf[ks], kf, s[t2], 0, 0, 0);
            }
        }
        // per-row max (4-step cross-lane), defer-max rescale check
        float pmax[4];
#pragma unroll
        for (int r = 0; r < 4; r++) {
            float mx = fmaxf(fmaxf(s[0][r], s[1][r]), fmaxf(s[2][r], s[3][r]));
            mx *= SCL;
#pragma unroll
            for (int off = 1; off < 16; off <<= 1) mx = fmaxf(mx, __shfl_xor(mx, off));
            pmax[r] = mx;
        }
        bool need = (pmax[0] > mrun[0] + 8.f) || (pmax[1] > mrun[1] + 8.f) ||
                    (pmax[2] > mrun[2] + 8.f) || (pmax[3] > mrun[3] + 8.f);
        if (__ballot(need)) {
#pragma unroll
            for (int r = 0; r < 4; r++) {
                float mnew = fmaxf(mrun[r], pmax[r]);
                float rf = exp2f(mrun[r] - mnew);
                mrun[r] = mnew;
                ls[r] *= rf;
#pragma unroll
                for (int nt = 0; nt < 4; nt++) o[nt][r] *= rf;
            }
        }
#pragma unroll
        for (int t2 = 0; t2 < 4; t2++)
#pragma unroll
            for (int r = 0; r < 4; r++) s[t2][r] = exp2f(s[t2][r] * SCL - mrun[r]);
        // P -> wave-private swizzled LDS
#pragma unroll
        for (int t2 = 0; t2 < 4; t2++) {
            int colc = c + t2 * 16;
            int chunk2 = colc >> 3;
#pragma unroll
            for (int r = 0; r < 4; r++) {
                int row = g * 4 + r;
                Pw[row * 64 + ((chunk2 ^ (row & 7)) << 3) + (colc & 7)] = f2bf(s[t2][r]);
            }
        }
        // O += P @ V ; ls += P @ ones
#pragma unroll
        for (int ks = 0; ks < 2; ++ks) {
            int pch = (ks * 4 + g) ^ (c & 7);
            bf16x8 pa = *(const bf16x8*)&Pw[c * 64 + pch * 8];
            ls = __builtin_amdgcn_mfma_f32_16x16x32_bf16(pa, onesf, ls, 0, 0, 0);
#pragma unroll
            for (int nt = 0; nt < 4; nt++) {
                int vrow = nt * 16 + c;
                int vch = (ks * 4 + g) ^ (vrow & 7);
                bf16x8 vb = *(const bf16x8*)&Vsm[pbuf][vrow * 64 + vch * 8];
                o[nt] = __builtin_amdgcn_mfma_f32_16x16x32_bf16(pa, vb, o[nt], 0, 0, 0);
            }
        }
        __builtin_amdgcn_s_barrier();      // all waves done reading buf[pbuf]
    }
    // store unnormalized partials
    long prow0 = ((long)(chunk * 32 + p_) * 512 + qb0 + w * 16);
#pragma unroll
    for (int r = 0; r < 4; r++) {
        long row = prow0 + g * 4 + r;
#pragma unroll
        for (int nt = 0; nt < 4; nt++)
            Op[row * 64 + nt * 16 + c] = o[nt][r];
        if (c == 0) ML[row] = make_float2(mrun[r], ls[r]);
    }
}

// ---------------- combine: merge 4 kv-chunk partials ----------------
__global__ __launch_bounds__(256) void attn_combine(const float* __restrict__ Op,
                                                    const float2* __restrict__ ML,
                                                    u16* __restrict__ O) {
    int tid = threadIdx.x;
    int w = tid >> 6, l = tid & 63;
    long rid = (long)blockIdx.x * 4 + w;   // 0..16383 : (p_, row)
    int p_ = (int)(rid >> 9);
    int row = (int)(rid & 511);
    int b = p_ >> 3, h = p_ & 7;
    float2 m[4];
#pragma unroll
    for (int cc = 0; cc < 4; cc++) m[cc] = ML[((long)(cc * 32 + p_) * 512 + row)];
    float mstar = fmaxf(fmaxf(m[0].x, m[1].x), fmaxf(m[2].x, m[3].x));
    float wsum = 0.f, acc = 0.f;
#pragma unroll
    for (int cc = 0; cc < 4; cc++) {
        float wgt = exp2f(m[cc].x - mstar);
        wsum += wgt * m[cc].y;
        acc += wgt * Op[((long)(cc * 32 + p_) * 512 + row) * 64 + l];
    }
    O[((long)(b * 512 + row)) * 512 + h * 64 + l] = f2bf(acc / wsum);
}

// ---------------- launch ----------------

extern "C" void kernel_launch(void* const* d_in, const int* in_sizes, int n_in,
                              void* d_out, int out_size, void* d_ws, size_t ws_size,
                              hipStream_t stream) {
    const float* x = (const float*)d_in[0];
    const float* ctx = (const float*)d_in[1];
    const float* Wq = (const float*)d_in[2];
    const float* Wkv = (const float*)d_in[3];
    const float* Wout = (const float*)d_in[4];
    float* out = (float*)d_out;

    char* ws = (char*)d_ws;
    size_t off = 0;
    auto alloc = [&](size_t bytes) {
        size_t r = off;
        off += (bytes + 255) & ~(size_t)255;
        return r;
    };
    u16* ctxb = (u16*)(ws + alloc(4L * 4608 * 512 * 2));
    u16* wqb = (u16*)(ws + alloc(512L * 512 * 2));
    u16* wkvb = (u16*)(ws + alloc(1024L * 512 * 2));
    u16* woutb = (u16*)(ws + alloc(512L * 512 * 2));
    u16* qb = (u16*)(ws + alloc(2048L * 512 * 2));
    u16* kb = (u16*)(ws + alloc(4L * 4608 * 512 * 2));
    u16* vtb = (u16*)(ws + alloc(4L * 8 * 64 * 4608 * 2));
    u16* aob = (u16*)(ws + alloc(2048L * 512 * 2));
    float* opb = (float*)(ws + alloc(4L * 32 * 512 * 64 * 4));   // 16.8 MB
    float2* mlb = (float2*)(ws + alloc(4L * 32 * 512 * 8));      // 0.5 MB

    build_ctxb<<<dim3(4608), dim3(256), 0, stream>>>(x, ctx, ctxb);
    cast_bf16<<<dim3(128), dim3(256), 0, stream>>>(Wq, wqb);
    cast_bf16<<<dim3(256), dim3(256), 0, stream>>>(Wkv, wkvb);
    cast_bf16<<<dim3(128), dim3(256), 0, stream>>>(Wout, woutb);

    gemm_bt<u16, false><<<dim3(4, 16), dim3(256), 0, stream>>>(
        ctxb, wqb, qb, nullptr, 512, 512, (long)4608 * 512);
    gemm_bt<u16, true><<<dim3(8, 144), dim3(256), 0, stream>>>(
        ctxb, wkvb, kb, vtb, 512, 4608, (long)4608 * 512);
    attn_kern<<<dim3(1024), dim3(256), 0, stream>>>(qb, kb, vtb, opb, mlb);
    attn_combine<<<dim3(4096), dim3(256), 0, stream>>>(opb, mlb, aob);
    gemm_bt<float, false><<<dim3(4, 16), dim3(256), 0, stream>>>(
        aob, woutb, out, nullptr, 512, 2048, (long)2048 * 512);
}

// Round 4
// 199.273 us; speedup vs baseline: 1.5062x; 1.0675x over previous
//
#include <hip/hip_runtime.h>
#include <hip/hip_bf16.h>
#include <cstdint>

#define DEVI __device__ __forceinline__

typedef unsigned short u16;
typedef unsigned int u32;
typedef __attribute__((ext_vector_type(8))) short bf16x8;
typedef __attribute__((ext_vector_type(4))) float f32x4;
typedef __attribute__((ext_vector_type(4))) int i32x4;

DEVI u16 f2bf(float f) {
    union { float f; u32 u; } v; v.f = f;
    u32 r = v.u + 0x7fffu + ((v.u >> 16) & 1u);
    return (u16)(r >> 16);
}
DEVI u32 pk2(float a, float b) { return (u32)f2bf(a) | ((u32)f2bf(b) << 16); }

DEVI u32 cvtpk_bf16(float lo, float hi) {
    u32 r;
    asm("v_cvt_pk_bf16_f32 %0, %1, %2" : "=v"(r) : "v"(lo), "v"(hi));
    return r;
}

DEVI void gload_lds16(const void* g, void* l) {
    __builtin_amdgcn_global_load_lds(
        (const __attribute__((address_space(1))) u32*)(uintptr_t)g,
        (__attribute__((address_space(3))) u32*)(u32)(uintptr_t)l,
        16, 0, 0);
}

// ---------------- prep kernels ----------------

__global__ __launch_bounds__(256) void build_ctxb(const float* __restrict__ x,
                                                  const float* __restrict__ ctx,
                                                  u16* __restrict__ out) {
    int idx = blockIdx.x * 256 + threadIdx.x;
    long e0 = (long)idx * 8;
    int b = (int)(e0 / (4608L * 512));
    long rem = e0 % (4608L * 512);
    int m = (int)(rem / 512);
    int d = (int)(rem % 512);
    const float* src = (m < 512) ? (x + ((long)b * 512 + m) * 512 + d)
                                 : (ctx + ((long)b * 4096 + (m - 512)) * 512 + d);
    float4 a = *(const float4*)src;
    float4 c = *(const float4*)(src + 4);
    uint4 u;
    u.x = pk2(a.x, a.y); u.y = pk2(a.z, a.w);
    u.z = pk2(c.x, c.y); u.w = pk2(c.z, c.w);
    *(uint4*)&out[e0] = u;
}

__global__ __launch_bounds__(256) void cast_bf16(const float* __restrict__ s,
                                                 u16* __restrict__ d) {
    int i = blockIdx.x * 256 + threadIdx.x;
    const float4* s4 = (const float4*)s;
    float4 a = s4[i * 2], b = s4[i * 2 + 1];
    uint4 u;
    u.x = pk2(a.x, a.y); u.y = pk2(a.z, a.w);
    u.z = pk2(b.x, b.y); u.w = pk2(b.z, b.w);
    ((uint4*)d)[i] = u;
}

// ---------------- GEMM: C[M,N] = A[M,K] @ B[N,K]^T, K=512, bf16 in ----------------
template <typename CT, bool SPLITV>
__global__ __launch_bounds__(256) void gemm_bt(const u16* __restrict__ A,
                                               const u16* __restrict__ B,
                                               CT* __restrict__ C,
                                               u16* __restrict__ VT,
                                               int N, int rpb, long bstride) {
    const int K = 512;
    __shared__ u16 Asm[2][128 * 64];
    __shared__ u16 Bsm[2][128 * 64];
    int tid = threadIdx.x;
    int w = tid >> 6, l = tid & 63;
    int g = l >> 4, c = l & 15;
    int wr = w >> 1, wc = w & 1;
    long r0 = (long)blockIdx.y * 128;
    long arow0 = (r0 / rpb) * bstride + (r0 % rpb) * K;
    int n0 = blockIdx.x * 128;

    f32x4 acc[4][4];
#pragma unroll
    for (int i = 0; i < 4; i++)
#pragma unroll
        for (int j = 0; j < 4; j++) acc[i][j] = (f32x4){0.f, 0.f, 0.f, 0.f};

    int srow = l >> 3;
    int sch = l & 7;

    auto stage = [&](int kt, int bb) {
#pragma unroll
        for (int i = 0; i < 4; i++) {
            int c2 = w * 4 + i;
            int row = c2 * 8 + srow;
            int sc = sch ^ (row & 7);
            gload_lds16(A + arow0 + (long)row * K + kt * 64 + sc * 8,
                        &Asm[bb][c2 * 512 + (l << 3)]);
            gload_lds16(B + (long)(n0 + row) * K + kt * 64 + sc * 8,
                        &Bsm[bb][c2 * 512 + (l << 3)]);
        }
    };

    stage(0, 0);
#pragma unroll 2
    for (int kt = 0; kt < 8; ++kt) {
        int pb = kt & 1;
        if (kt < 7) {
            stage(kt + 1, pb ^ 1);
            asm volatile("s_waitcnt vmcnt(8)" ::: "memory");
        } else {
            asm volatile("s_waitcnt vmcnt(0)" ::: "memory");
        }
        __builtin_amdgcn_s_barrier();
        __builtin_amdgcn_sched_barrier(0);
#pragma unroll
        for (int ks = 0; ks < 2; ++ks) {
            bf16x8 af[4], bfr[4];
#pragma unroll
            for (int mt = 0; mt < 4; ++mt) {
                int row = wr * 64 + mt * 16 + c;
                int ch = (ks * 4 + g) ^ (row & 7);
                af[mt] = *(const bf16x8*)&Asm[pb][row * 64 + ch * 8];
            }
#pragma unroll
            for (int nt = 0; nt < 4; ++nt) {
                int row = wc * 64 + nt * 16 + c;
                int ch = (ks * 4 + g) ^ (row & 7);
                bfr[nt] = *(const bf16x8*)&Bsm[pb][row * 64 + ch * 8];
            }
#pragma unroll
            for (int mt = 0; mt < 4; ++mt)
#pragma unroll
                for (int nt = 0; nt < 4; ++nt)
                    acc[mt][nt] = __builtin_amdgcn_mfma_f32_16x16x32_bf16(
                        af[mt], bfr[nt], acc[mt][nt], 0, 0, 0);
        }
        __builtin_amdgcn_s_barrier();
    }

    if constexpr (SPLITV) {
        if (n0 >= 512) {
            int b2 = (int)(r0 / rpb);
            int mb = (int)(r0 - (long)b2 * rpb) + wr * 64;
#pragma unroll
            for (int mt = 0; mt < 4; ++mt) {
#pragma unroll
                for (int nt = 0; nt < 4; ++nt) {
                    int colv = (n0 - 512) + wc * 64 + nt * 16 + c;
                    int hh = colv >> 6, dd = colv & 63;
                    long ob = ((long)(b2 * 8 + hh) * 64 + dd) * 4608 + mb + mt * 16 + g * 4;
                    ushort4 pk;
                    pk.x = f2bf(acc[mt][nt][0]);
                    pk.y = f2bf(acc[mt][nt][1]);
                    pk.z = f2bf(acc[mt][nt][2]);
                    pk.w = f2bf(acc[mt][nt][3]);
                    *(ushort4*)&VT[ob] = pk;
                }
            }
            return;
        }
    }
#pragma unroll
    for (int mt = 0; mt < 4; ++mt) {
#pragma unroll
        for (int r = 0; r < 4; ++r) {
            long row = r0 + wr * 64 + mt * 16 + g * 4 + r;
#pragma unroll
            for (int nt = 0; nt < 4; ++nt) {
                int col = n0 + wc * 64 + nt * 16 + c;
                float v = acc[mt][nt][r];
                if constexpr (sizeof(CT) == 2) {
                    C[row * (long)N + col] = (CT)f2bf(v);
                } else {
                    C[row * (long)N + col] = v;
                }
            }
        }
    }
}

// ---------------- flash attention, split-KV x4, swapped-operand ----------------
// S^T = mfma(K,Q): lane(g,c) holds S^T[kv=t2*16+g*4+r][q=c] -> softmax fully
// in-lane (15-op tree + 2 shuffles). P routed to PV's B-operand in-register via
// cvt_pk_bf16 + ds_bpermute (no P LDS round-trip). O^T = mfma(V,P).
__global__ __launch_bounds__(256) void attn_kern(const u16* __restrict__ Q,
                                                 const u16* __restrict__ KB,
                                                 const u16* __restrict__ VT,
                                                 float* __restrict__ Op,
                                                 float2* __restrict__ ML) {
    __shared__ u16 Ksm[2][64 * 64];
    __shared__ u16 Vsm[2][64 * 64];
    int tid = threadIdx.x;
    int w = tid >> 6, l = tid & 63;
    int g = l >> 4, c = l & 15;
    int id = blockIdx.x;
    int u = (id & 7) | ((id >> 6) << 3);   // unit (b,h,chunk) 0..127
    int qi = (id >> 3) & 7;
    int p_ = u >> 2, chunk = u & 3;
    int b = p_ >> 3, h = p_ & 7;
    int qb0 = qi * 64;
    const int NT = 18;
    int it0 = chunk * NT;

    bf16x8 qf[2];   // B-operand fragment: Q^T[d=ks*32+g*8+j][q=c]
    {
        long qrow = (long)(b * 512 + qb0 + w * 16 + c);
#pragma unroll
        for (int ks = 0; ks < 2; ++ks)
            qf[ks] = *(const bf16x8*)&Q[qrow * 512 + h * 64 + ks * 32 + g * 8];
    }
    f32x4 o[4];     // O^T[d=nt*16+g*4+r][q=c]
#pragma unroll
    for (int nt = 0; nt < 4; nt++) o[nt] = (f32x4){0.f, 0.f, 0.f, 0.f};
    float mrun = -1e30f, lrun = 0.f;

    const float SCL = 0.125f * 1.44269504f;
    int srow8 = l >> 3, sch = l & 7;
    const long kbase = (long)b * 4608 * 512 + h * 64;
    const long vtbase = (long)(b * 8 + h) * 64 * 4608;

    // bpermute routing lanes: sources ((2g)&3,c) and ((2g+1)&3,c)
    int g2 = g << 1;
    int srcA = ((g2 & 3) << 4) | c;
    int srcB = (((g2 | 1) & 3) << 4) | c;
    bool hiT2 = (g >> 1) != 0;

    auto stage = [&](int it, int bb) {
#pragma unroll
        for (int i = 0; i < 2; i++) {
            int c2 = w * 2 + i;
            int row = c2 * 8 + srow8;
            int sc = sch ^ (row & 7);
            gload_lds16(KB + kbase + (long)(it * 64 + row) * 512 + sc * 8,
                        &Ksm[bb][c2 * 512 + (l << 3)]);
            gload_lds16(VT + vtbase + (long)row * 4608 + it * 64 + sc * 8,
                        &Vsm[bb][c2 * 512 + (l << 3)]);
        }
    };

    stage(it0, 0);
#pragma unroll 2
    for (int t = 0; t < NT; ++t) {
        int pbuf = t & 1;
        if (t + 1 < NT) {
            stage(it0 + t + 1, pbuf ^ 1);
            asm volatile("s_waitcnt vmcnt(4)" ::: "memory");
        } else {
            asm volatile("s_waitcnt vmcnt(0)" ::: "memory");
        }
        __builtin_amdgcn_s_barrier();      // tile t resident everywhere
        __builtin_amdgcn_sched_barrier(0);

        // S^T = K @ Q^T
        f32x4 st[4];
#pragma unroll
        for (int t2 = 0; t2 < 4; t2++) st[t2] = (f32x4){0.f, 0.f, 0.f, 0.f};
        __builtin_amdgcn_s_setprio(1);
#pragma unroll
        for (int ks = 0; ks < 2; ++ks) {
#pragma unroll
            for (int t2 = 0; t2 < 4; t2++) {
                int row = t2 * 16 + c;
                int ch = (ks * 4 + g) ^ (row & 7);
                bf16x8 kf = *(const bf16x8*)&Ksm[pbuf][row * 64 + ch * 8];
                st[t2] = __builtin_amdgcn_mfma_f32_16x16x32_bf16(kf, qf[ks], st[t2], 0, 0, 0);
            }
        }
        __builtin_amdgcn_s_setprio(0);

        // in-lane max over 16 kv values (all for q=c), then 2 shuffles across g
        float mx01 = fmaxf(fmaxf(st[0][0], st[0][1]), fmaxf(st[0][2], st[0][3]));
        float mx23 = fmaxf(fmaxf(st[1][0], st[1][1]), fmaxf(st[1][2], st[1][3]));
        float mx45 = fmaxf(fmaxf(st[2][0], st[2][1]), fmaxf(st[2][2], st[2][3]));
        float mx67 = fmaxf(fmaxf(st[3][0], st[3][1]), fmaxf(st[3][2], st[3][3]));
        float mx = fmaxf(fmaxf(mx01, mx23), fmaxf(mx45, mx67)) * SCL;
        mx = fmaxf(mx, __shfl_xor(mx, 16));
        mx = fmaxf(mx, __shfl_xor(mx, 32));

        bool need = mx > mrun + 8.f;       // defer-max (T13)
        if (__ballot(need)) {
            float mnew = fmaxf(mrun, mx);
            float rf = exp2f(mrun - mnew);
            mrun = mnew;
            lrun *= rf;
#pragma unroll
            for (int nt = 0; nt < 4; nt++)
#pragma unroll
                for (int r = 0; r < 4; r++) o[nt][r] *= rf;
        }
#pragma unroll
        for (int t2 = 0; t2 < 4; t2++)
#pragma unroll
            for (int r = 0; r < 4; r++) st[t2][r] = exp2f(st[t2][r] * SCL - mrun);

        float s01 = (st[0][0] + st[0][1]) + (st[0][2] + st[0][3]);
        float s23 = (st[1][0] + st[1][1]) + (st[1][2] + st[1][3]);
        float s45 = (st[2][0] + st[2][1]) + (st[2][2] + st[2][3]);
        float s67 = (st[3][0] + st[3][1]) + (st[3][2] + st[3][3]);
        float su = (s01 + s23) + (s45 + s67);
        su += __shfl_xor(su, 16);
        su += __shfl_xor(su, 32);
        lrun += su;

        // pack P to bf16 pairs: u01/u23[t2] = {r0,r1}/{r2,r3}
        u32 u01[4], u23[4];
#pragma unroll
        for (int t2 = 0; t2 < 4; t2++) {
            u01[t2] = cvtpk_bf16(st[t2][0], st[t2][1]);
            u23[t2] = cvtpk_bf16(st[t2][2], st[t2][3]);
        }
        // route to B-operand fragments via bpermute + select
        bf16x8 pbf[2];
#pragma unroll
        for (int ks = 0; ks < 2; ++ks) {
            u32 a0 = (u32)__shfl((int)u01[2 * ks], srcA);
            u32 a1 = (u32)__shfl((int)u01[2 * ks + 1], srcA);
            u32 b0 = (u32)__shfl((int)u23[2 * ks], srcA);
            u32 b1 = (u32)__shfl((int)u23[2 * ks + 1], srcA);
            u32 c0 = (u32)__shfl((int)u01[2 * ks], srcB);
            u32 c1 = (u32)__shfl((int)u01[2 * ks + 1], srcB);
            u32 d0 = (u32)__shfl((int)u23[2 * ks], srcB);
            u32 d1 = (u32)__shfl((int)u23[2 * ks + 1], srcB);
            i32x4 vv;
            vv[0] = (int)(hiT2 ? a1 : a0);
            vv[1] = (int)(hiT2 ? b1 : b0);
            vv[2] = (int)(hiT2 ? c1 : c0);
            vv[3] = (int)(hiT2 ? d1 : d0);
            pbf[ks] = __builtin_bit_cast(bf16x8, vv);
        }

        // O^T += V^T @ P^T
        __builtin_amdgcn_s_setprio(1);
#pragma unroll
        for (int ks = 0; ks < 2; ++ks) {
#pragma unroll
            for (int nt = 0; nt < 4; nt++) {
                int vrow = nt * 16 + c;
                int vch = (ks * 4 + g) ^ (vrow & 7);
                bf16x8 vb = *(const bf16x8*)&Vsm[pbuf][vrow * 64 + vch * 8];
                o[nt] = __builtin_amdgcn_mfma_f32_16x16x32_bf16(vb, pbf[ks], o[nt], 0, 0, 0);
            }
        }
        __builtin_amdgcn_s_setprio(0);
        __builtin_amdgcn_s_barrier();      // all waves done reading buf[pbuf]
    }

    // epilogue: lane holds O^T[d][q=c] -> store rows of Op
    long prow = (long)(chunk * 32 + p_) * 512 + qb0 + w * 16;
#pragma unroll
    for (int nt = 0; nt < 4; nt++)
        *(f32x4*)&Op[(prow + c) * 64 + nt * 16 + g * 4] = o[nt];
    if (g == 0) ML[prow + c] = make_float2(mrun, lrun);
}

// ---------------- combine: merge 4 kv-chunk partials ----------------
__global__ __launch_bounds__(256) void attn_combine(const float* __restrict__ Op,
                                                    const float2* __restrict__ ML,
                                                    u16* __restrict__ O) {
    int tid = threadIdx.x;
    int w = tid >> 6, l = tid & 63;
    long rid = (long)blockIdx.x * 4 + w;   // 0..16383 : (p_, row)
    int p_ = (int)(rid >> 9);
    int row = (int)(rid & 511);
    int b = p_ >> 3, h = p_ & 7;
    float2 m[4];
#pragma unroll
    for (int cc = 0; cc < 4; cc++) m[cc] = ML[((long)(cc * 32 + p_) * 512 + row)];
    float mstar = fmaxf(fmaxf(m[0].x, m[1].x), fmaxf(m[2].x, m[3].x));
    float wsum = 0.f, acc = 0.f;
#pragma unroll
    for (int cc = 0; cc < 4; cc++) {
        float wgt = exp2f(m[cc].x - mstar);
        wsum += wgt * m[cc].y;
        acc += wgt * Op[((long)(cc * 32 + p_) * 512 + row) * 64 + l];
    }
    O[((long)(b * 512 + row)) * 512 + h * 64 + l] = f2bf(acc / wsum);
}

// ---------------- launch ----------------

extern "C" void kernel_launch(void* const* d_in, const int* in_sizes, int n_in,
                              void* d_out, int out_size, void* d_ws, size_t ws_size,
                              hipStream_t stream) {
    const float* x = (const float*)d_in[0];
    const float* ctx = (const float*)d_in[1];
    const float* Wq = (const float*)d_in[2];
    const float* Wkv = (const float*)d_in[3];
    const float* Wout = (const float*)d_in[4];
    float* out = (float*)d_out;

    char* ws = (char*)d_ws;
    size_t off = 0;
    auto alloc = [&](size_t bytes) {
        size_t r = off;
        off += (bytes + 255) & ~(size_t)255;
        return r;
    };
    u16* ctxb = (u16*)(ws + alloc(4L * 4608 * 512 * 2));
    u16* wqb = (u16*)(ws + alloc(512L * 512 * 2));
    u16* wkvb = (u16*)(ws + alloc(1024L * 512 * 2));
    u16* woutb = (u16*)(ws + alloc(512L * 512 * 2));
    u16* qb = (u16*)(ws + alloc(2048L * 512 * 2));
    u16* kb = (u16*)(ws + alloc(4L * 4608 * 512 * 2));
    u16* vtb = (u16*)(ws + alloc(4L * 8 * 64 * 4608 * 2));
    u16* aob = (u16*)(ws + alloc(2048L * 512 * 2));
    float* opb = (float*)(ws + alloc(4L * 32 * 512 * 64 * 4));   // 16.8 MB
    float2* mlb = (float2*)(ws + alloc(4L * 32 * 512 * 8));      // 0.5 MB

    build_ctxb<<<dim3(4608), dim3(256), 0, stream>>>(x, ctx, ctxb);
    cast_bf16<<<dim3(128), dim3(256), 0, stream>>>(Wq, wqb);
    cast_bf16<<<dim3(256), dim3(256), 0, stream>>>(Wkv, wkvb);
    cast_bf16<<<dim3(128), dim3(256), 0, stream>>>(Wout, woutb);

    gemm_bt<u16, false><<<dim3(4, 16), dim3(256), 0, stream>>>(
        ctxb, wqb, qb, nullptr, 512, 512, (long)4608 * 512);
    gemm_bt<u16, true><<<dim3(8, 144), dim3(256), 0, stream>>>(
        ctxb, wkvb, kb, vtb, 512, 4608, (long)4608 * 512);
    attn_kern<<<dim3(1024), dim3(256), 0, stream>>>(qb, kb, vtb, opb, mlb);
    attn_combine<<<dim3(4096), dim3(256), 0, stream>>>(opb, mlb, aob);
    gemm_bt<float, false><<<dim3(4, 16), dim3(256), 0, stream>>>(
        aob, woutb, out, nullptr, 512, 2048, (long)2048 * 512);
}

// Round 6
// 189.562 us; speedup vs baseline: 1.5834x; 1.0512x over previous
//
#include <hip/hip_runtime.h>
#include <hip/hip_bf16.h>
#include <cstdint>

#define DEVI __device__ __forceinline__

typedef unsigned short u16;
typedef unsigned int u32;
typedef __attribute__((ext_vector_type(8))) short bf16x8;
typedef __attribute__((ext_vector_type(4))) float f32x4;
typedef __attribute__((ext_vector_type(4))) int i32x4;

DEVI u16 f2bf(float f) {
    union { float f; u32 u; } v; v.f = f;
    u32 r = v.u + 0x7fffu + ((v.u >> 16) & 1u);
    return (u16)(r >> 16);
}
DEVI u32 pk2(float a, float b) { return (u32)f2bf(a) | ((u32)f2bf(b) << 16); }

DEVI u32 cvtpk_bf16(float lo, float hi) {
    u32 r;
    asm("v_cvt_pk_bf16_f32 %0, %1, %2" : "=v"(r) : "v"(lo), "v"(hi));
    return r;
}

DEVI void gload_lds16(const void* g, void* l) {
    __builtin_amdgcn_global_load_lds(
        (const __attribute__((address_space(1))) u32*)(uintptr_t)g,
        (__attribute__((address_space(3))) u32*)(u32)(uintptr_t)l,
        16, 0, 0);
}

// ---------------- fused prep: build ctxb + cast 3 weight mats ----------------
__global__ __launch_bounds__(256) void prep_all(const float* __restrict__ x,
                                                const float* __restrict__ ctx,
                                                const float* __restrict__ Wq,
                                                const float* __restrict__ Wkv,
                                                const float* __restrict__ Wout,
                                                u16* __restrict__ ctxb,
                                                u16* __restrict__ wqb,
                                                u16* __restrict__ wkvb,
                                                u16* __restrict__ woutb) {
    int id = blockIdx.x;
    int tid = threadIdx.x;
    if (id < 4608) {                       // ctxb build
        int idx = id * 256 + tid;
        long e0 = (long)idx * 8;
        int b = (int)(e0 / (4608L * 512));
        long rem = e0 % (4608L * 512);
        int m = (int)(rem / 512);
        int d = (int)(rem % 512);
        const float* src = (m < 512) ? (x + ((long)b * 512 + m) * 512 + d)
                                     : (ctx + ((long)b * 4096 + (m - 512)) * 512 + d);
        float4 a = *(const float4*)src;
        float4 c = *(const float4*)(src + 4);
        uint4 u;
        u.x = pk2(a.x, a.y); u.y = pk2(a.z, a.w);
        u.z = pk2(c.x, c.y); u.w = pk2(c.z, c.w);
        *(uint4*)&ctxb[e0] = u;
        return;
    }
    const float* s;
    u16* d;
    int i;
    if (id < 4736)      { s = Wq;   d = wqb;   i = (id - 4608) * 256 + tid; }
    else if (id < 4992) { s = Wkv;  d = wkvb;  i = (id - 4736) * 256 + tid; }
    else                { s = Wout; d = woutb; i = (id - 4992) * 256 + tid; }
    const float4* s4 = (const float4*)s;
    float4 a = s4[i * 2], b = s4[i * 2 + 1];
    uint4 u;
    u.x = pk2(a.x, a.y); u.y = pk2(a.z, a.w);
    u.z = pk2(b.x, b.y); u.w = pk2(b.z, b.w);
    ((uint4*)d)[i] = u;
}

// ---------------- big GEMM: 128x256 tile, 8 waves, BK=64, dbuf ----------------
// blockIdx.y < 144: kv projection (A=ctxb rows, B=Wkv, K-half->kb, V-half->vtb^T)
// blockIdx.y >= 144: q projection (A=ctxb x-rows, B=Wq, C->qb), only bx<2 active.
__global__ __launch_bounds__(512) void gemm_kvq(const u16* __restrict__ ctxb,
                                                const u16* __restrict__ wkvb,
                                                const u16* __restrict__ wqb,
                                                u16* __restrict__ kb,
                                                u16* __restrict__ vtb,
                                                u16* __restrict__ qb) {
    const int K = 512;
    __shared__ u16 Asm[2][128 * 64];   // 16KB x2
    __shared__ u16 Bsm[2][256 * 64];   // 32KB x2
    int tid = threadIdx.x;
    int w = tid >> 6, l = tid & 63;
    int g = l >> 4, c = l & 15;
    int wr = w >> 2, wc = w & 3;       // 2x4 wave grid over 128x256

    const u16* B;
    u16* C;
    long r0, arow0;
    int rpb;
    bool isq = (blockIdx.y >= 144);
    if (isq) {
        if (blockIdx.x >= 2) return;
        r0 = (long)(blockIdx.y - 144) * 128;
        rpb = 512;
        B = wqb;
        C = qb;
    } else {
        r0 = (long)blockIdx.y * 128;
        rpb = 4608;
        B = wkvb;
        C = kb;
    }
    arow0 = (r0 / rpb) * (4608L * 512) + (r0 % rpb) * K;
    int n0 = blockIdx.x * 256;

    f32x4 acc[4][4];
#pragma unroll
    for (int i = 0; i < 4; i++)
#pragma unroll
        for (int j = 0; j < 4; j++) acc[i][j] = (f32x4){0.f, 0.f, 0.f, 0.f};

    int srow = l >> 3;
    int sch = l & 7;

    auto stage = [&](int kt, int bb) {
#pragma unroll
        for (int i = 0; i < 2; i++) {       // A: 16 chunks, 2/wave
            int c2 = w * 2 + i;
            int row = c2 * 8 + srow;
            int sc = sch ^ (row & 7);
            gload_lds16(ctxb + arow0 + (long)row * K + kt * 64 + sc * 8,
                        &Asm[bb][c2 * 512 + (l << 3)]);
        }
#pragma unroll
        for (int i = 0; i < 4; i++) {       // B: 32 chunks, 4/wave
            int c2 = w * 4 + i;
            int row = c2 * 8 + srow;
            int sc = sch ^ (row & 7);
            gload_lds16(B + (long)(n0 + row) * K + kt * 64 + sc * 8,
                        &Bsm[bb][c2 * 512 + (l << 3)]);
        }
    };

    stage(0, 0);
#pragma unroll 2
    for (int kt = 0; kt < 8; ++kt) {
        int pb = kt & 1;
        if (kt < 7) {
            stage(kt + 1, pb ^ 1);
            asm volatile("s_waitcnt vmcnt(6)" ::: "memory");
        } else {
            asm volatile("s_waitcnt vmcnt(0)" ::: "memory");
        }
        __builtin_amdgcn_s_barrier();
        __builtin_amdgcn_sched_barrier(0);
#pragma unroll
        for (int ks = 0; ks < 2; ++ks) {
            bf16x8 af[4], bfr[4];
#pragma unroll
            for (int mt = 0; mt < 4; ++mt) {
                int row = wr * 64 + mt * 16 + c;
                int ch = (ks * 4 + g) ^ (row & 7);
                af[mt] = *(const bf16x8*)&Asm[pb][row * 64 + ch * 8];
            }
#pragma unroll
            for (int nt = 0; nt < 4; ++nt) {
                int row = wc * 64 + nt * 16 + c;
                int ch = (ks * 4 + g) ^ (row & 7);
                bfr[nt] = *(const bf16x8*)&Bsm[pb][row * 64 + ch * 8];
            }
            __builtin_amdgcn_s_setprio(1);
#pragma unroll
            for (int mt = 0; mt < 4; ++mt)
#pragma unroll
                for (int nt = 0; nt < 4; ++nt)
                    acc[mt][nt] = __builtin_amdgcn_mfma_f32_16x16x32_bf16(
                        af[mt], bfr[nt], acc[mt][nt], 0, 0, 0);
            __builtin_amdgcn_s_setprio(0);
        }
        __builtin_amdgcn_s_barrier();
    }

    if (!isq && n0 >= 512) {               // V half -> VT[b,h,d,m] transposed
        int b2 = (int)(r0 / 4608);
        int mb = (int)(r0 - (long)b2 * 4608) + wr * 64;
#pragma unroll
        for (int mt = 0; mt < 4; ++mt) {
#pragma unroll
            for (int nt = 0; nt < 4; ++nt) {
                int colv = (n0 - 512) + wc * 64 + nt * 16 + c;
                int hh = colv >> 6, dd = colv & 63;
                long ob = ((long)(b2 * 8 + hh) * 64 + dd) * 4608 + mb + mt * 16 + g * 4;
                ushort4 pk;
                pk.x = f2bf(acc[mt][nt][0]);
                pk.y = f2bf(acc[mt][nt][1]);
                pk.z = f2bf(acc[mt][nt][2]);
                pk.w = f2bf(acc[mt][nt][3]);
                *(ushort4*)&vtb[ob] = pk;
            }
        }
        return;
    }
#pragma unroll
    for (int mt = 0; mt < 4; ++mt) {
#pragma unroll
        for (int r = 0; r < 4; ++r) {
            long row = r0 + wr * 64 + mt * 16 + g * 4 + r;
#pragma unroll
            for (int nt = 0; nt < 4; ++nt) {
                int col = n0 + wc * 64 + nt * 16 + c;
                C[row * 512 + col] = f2bf(acc[mt][nt][r]);
            }
        }
    }
}

// ---------------- out GEMM: C[M,512] = A[M,512] @ B[512,512]^T, f32 out ----------------
__global__ __launch_bounds__(256) void gemm_out(const u16* __restrict__ A,
                                                const u16* __restrict__ B,
                                                float* __restrict__ C) {
    const int K = 512;
    __shared__ u16 Asm[2][128 * 64];
    __shared__ u16 Bsm[2][128 * 64];
    int tid = threadIdx.x;
    int w = tid >> 6, l = tid & 63;
    int g = l >> 4, c = l & 15;
    int wr = w >> 1, wc = w & 1;
    long r0 = (long)blockIdx.y * 128;
    long arow0 = r0 * K;
    int n0 = blockIdx.x * 128;

    f32x4 acc[4][4];
#pragma unroll
    for (int i = 0; i < 4; i++)
#pragma unroll
        for (int j = 0; j < 4; j++) acc[i][j] = (f32x4){0.f, 0.f, 0.f, 0.f};

    int srow = l >> 3;
    int sch = l & 7;

    auto stage = [&](int kt, int bb) {
#pragma unroll
        for (int i = 0; i < 4; i++) {
            int c2 = w * 4 + i;
            int row = c2 * 8 + srow;
            int sc = sch ^ (row & 7);
            gload_lds16(A + arow0 + (long)row * K + kt * 64 + sc * 8,
                        &Asm[bb][c2 * 512 + (l << 3)]);
            gload_lds16(B + (long)(n0 + row) * K + kt * 64 + sc * 8,
                        &Bsm[bb][c2 * 512 + (l << 3)]);
        }
    };

    stage(0, 0);
#pragma unroll 2
    for (int kt = 0; kt < 8; ++kt) {
        int pb = kt & 1;
        if (kt < 7) {
            stage(kt + 1, pb ^ 1);
            asm volatile("s_waitcnt vmcnt(8)" ::: "memory");
        } else {
            asm volatile("s_waitcnt vmcnt(0)" ::: "memory");
        }
        __builtin_amdgcn_s_barrier();
        __builtin_amdgcn_sched_barrier(0);
#pragma unroll
        for (int ks = 0; ks < 2; ++ks) {
            bf16x8 af[4], bfr[4];
#pragma unroll
            for (int mt = 0; mt < 4; ++mt) {
                int row = wr * 64 + mt * 16 + c;
                int ch = (ks * 4 + g) ^ (row & 7);
                af[mt] = *(const bf16x8*)&Asm[pb][row * 64 + ch * 8];
            }
#pragma unroll
            for (int nt = 0; nt < 4; ++nt) {
                int row = wc * 64 + nt * 16 + c;
                int ch = (ks * 4 + g) ^ (row & 7);
                bfr[nt] = *(const bf16x8*)&Bsm[pb][row * 64 + ch * 8];
            }
#pragma unroll
            for (int mt = 0; mt < 4; ++mt)
#pragma unroll
                for (int nt = 0; nt < 4; ++nt)
                    acc[mt][nt] = __builtin_amdgcn_mfma_f32_16x16x32_bf16(
                        af[mt], bfr[nt], acc[mt][nt], 0, 0, 0);
        }
        __builtin_amdgcn_s_barrier();
    }
#pragma unroll
    for (int mt = 0; mt < 4; ++mt) {
#pragma unroll
        for (int r = 0; r < 4; ++r) {
            long row = r0 + wr * 64 + mt * 16 + g * 4 + r;
#pragma unroll
            for (int nt = 0; nt < 4; ++nt) {
                int col = n0 + wc * 64 + nt * 16 + c;
                C[row * 512 + col] = acc[mt][nt][r];
            }
        }
    }
}

// ---------------- flash attention, split-KV x4, swapped-operand ----------------
__global__ __launch_bounds__(256) void attn_kern(const u16* __restrict__ Q,
                                                 const u16* __restrict__ KB,
                                                 const u16* __restrict__ VT,
                                                 float* __restrict__ Op,
                                                 float2* __restrict__ ML) {
    __shared__ u16 Ksm[2][64 * 64];
    __shared__ u16 Vsm[2][64 * 64];
    int tid = threadIdx.x;
    int w = tid >> 6, l = tid & 63;
    int g = l >> 4, c = l & 15;
    int id = blockIdx.x;
    int u = (id & 7) | ((id >> 6) << 3);   // unit (b,h,chunk) 0..127
    int qi = (id >> 3) & 7;
    int p_ = u >> 2, chunk = u & 3;
    int b = p_ >> 3, h = p_ & 7;
    int qb0 = qi * 64;
    const int NT = 18;
    int it0 = chunk * NT;

    bf16x8 qf[2];   // B-operand fragment: Q^T[d=ks*32+g*8+j][q=c]
    {
        long qrow = (long)(b * 512 + qb0 + w * 16 + c);
#pragma unroll
        for (int ks = 0; ks < 2; ++ks)
            qf[ks] = *(const bf16x8*)&Q[qrow * 512 + h * 64 + ks * 32 + g * 8];
    }
    f32x4 o[4];     // O^T[d=nt*16+g*4+r][q=c]
#pragma unroll
    for (int nt = 0; nt < 4; nt++) o[nt] = (f32x4){0.f, 0.f, 0.f, 0.f};
    float mrun = -1e30f, lrun = 0.f;

    const float SCL = 0.125f * 1.44269504f;
    int srow8 = l >> 3, sch = l & 7;
    const long kbase = (long)b * 4608 * 512 + h * 64;
    const long vtbase = (long)(b * 8 + h) * 64 * 4608;

    int g2 = g << 1;
    int srcA = ((g2 & 3) << 4) | c;
    int srcB = (((g2 | 1) & 3) << 4) | c;
    bool hiT2 = (g >> 1) != 0;

    auto stage = [&](int it, int bb) {
#pragma unroll
        for (int i = 0; i < 2; i++) {
            int c2 = w * 2 + i;
            int row = c2 * 8 + srow8;
            int sc = sch ^ (row & 7);
            gload_lds16(KB + kbase + (long)(it * 64 + row) * 512 + sc * 8,
                        &Ksm[bb][c2 * 512 + (l << 3)]);
            gload_lds16(VT + vtbase + (long)row * 4608 + it * 64 + sc * 8,
                        &Vsm[bb][c2 * 512 + (l << 3)]);
        }
    };

    stage(it0, 0);
#pragma unroll 2
    for (int t = 0; t < NT; ++t) {
        int pbuf = t & 1;
        if (t + 1 < NT) {
            stage(it0 + t + 1, pbuf ^ 1);
            asm volatile("s_waitcnt vmcnt(4)" ::: "memory");
        } else {
            asm volatile("s_waitcnt vmcnt(0)" ::: "memory");
        }
        __builtin_amdgcn_s_barrier();      // tile t resident everywhere
        __builtin_amdgcn_sched_barrier(0);

        // S^T = K @ Q^T
        f32x4 st[4];
#pragma unroll
        for (int t2 = 0; t2 < 4; t2++) st[t2] = (f32x4){0.f, 0.f, 0.f, 0.f};
        __builtin_amdgcn_s_setprio(1);
#pragma unroll
        for (int ks = 0; ks < 2; ++ks) {
#pragma unroll
            for (int t2 = 0; t2 < 4; t2++) {
                int row = t2 * 16 + c;
                int ch = (ks * 4 + g) ^ (row & 7);
                bf16x8 kf = *(const bf16x8*)&Ksm[pbuf][row * 64 + ch * 8];
                st[t2] = __builtin_amdgcn_mfma_f32_16x16x32_bf16(kf, qf[ks], st[t2], 0, 0, 0);
            }
        }
        __builtin_amdgcn_s_setprio(0);

        float mx01 = fmaxf(fmaxf(st[0][0], st[0][1]), fmaxf(st[0][2], st[0][3]));
        float mx23 = fmaxf(fmaxf(st[1][0], st[1][1]), fmaxf(st[1][2], st[1][3]));
        float mx45 = fmaxf(fmaxf(st[2][0], st[2][1]), fmaxf(st[2][2], st[2][3]));
        float mx67 = fmaxf(fmaxf(st[3][0], st[3][1]), fmaxf(st[3][2], st[3][3]));
        float mx = fmaxf(fmaxf(mx01, mx23), fmaxf(mx45, mx67)) * SCL;
        mx = fmaxf(mx, __shfl_xor(mx, 16));
        mx = fmaxf(mx, __shfl_xor(mx, 32));

        bool need = mx > mrun + 8.f;       // defer-max (T13)
        if (__ballot(need)) {
            float mnew = fmaxf(mrun, mx);
            float rf = exp2f(mrun - mnew);
            mrun = mnew;
            lrun *= rf;
#pragma unroll
            for (int nt = 0; nt < 4; nt++)
#pragma unroll
                for (int r = 0; r < 4; r++) o[nt][r] *= rf;
        }
#pragma unroll
        for (int t2 = 0; t2 < 4; t2++)
#pragma unroll
            for (int r = 0; r < 4; r++) st[t2][r] = exp2f(st[t2][r] * SCL - mrun);

        float s01 = (st[0][0] + st[0][1]) + (st[0][2] + st[0][3]);
        float s23 = (st[1][0] + st[1][1]) + (st[1][2] + st[1][3]);
        float s45 = (st[2][0] + st[2][1]) + (st[2][2] + st[2][3]);
        float s67 = (st[3][0] + st[3][1]) + (st[3][2] + st[3][3]);
        float su = (s01 + s23) + (s45 + s67);
        su += __shfl_xor(su, 16);
        su += __shfl_xor(su, 32);
        lrun += su;

        u32 u01[4], u23[4];
#pragma unroll
        for (int t2 = 0; t2 < 4; t2++) {
            u01[t2] = cvtpk_bf16(st[t2][0], st[t2][1]);
            u23[t2] = cvtpk_bf16(st[t2][2], st[t2][3]);
        }
        bf16x8 pbf[2];
#pragma unroll
        for (int ks = 0; ks < 2; ++ks) {
            u32 a0 = (u32)__shfl((int)u01[2 * ks], srcA);
            u32 a1 = (u32)__shfl((int)u01[2 * ks + 1], srcA);
            u32 b0 = (u32)__shfl((int)u23[2 * ks], srcA);
            u32 b1 = (u32)__shfl((int)u23[2 * ks + 1], srcA);
            u32 c0 = (u32)__shfl((int)u01[2 * ks], srcB);
            u32 c1 = (u32)__shfl((int)u01[2 * ks + 1], srcB);
            u32 d0 = (u32)__shfl((int)u23[2 * ks], srcB);
            u32 d1 = (u32)__shfl((int)u23[2 * ks + 1], srcB);
            i32x4 vv;
            vv[0] = (int)(hiT2 ? a1 : a0);
            vv[1] = (int)(hiT2 ? b1 : b0);
            vv[2] = (int)(hiT2 ? c1 : c0);
            vv[3] = (int)(hiT2 ? d1 : d0);
            pbf[ks] = __builtin_bit_cast(bf16x8, vv);
        }

        // O^T += V^T @ P^T
        __builtin_amdgcn_s_setprio(1);
#pragma unroll
        for (int ks = 0; ks < 2; ++ks) {
#pragma unroll
            for (int nt = 0; nt < 4; nt++) {
                int vrow = nt * 16 + c;
                int vch = (ks * 4 + g) ^ (vrow & 7);
                bf16x8 vb = *(const bf16x8*)&Vsm[pbuf][vrow * 64 + vch * 8];
                o[nt] = __builtin_amdgcn_mfma_f32_16x16x32_bf16(vb, pbf[ks], o[nt], 0, 0, 0);
            }
        }
        __builtin_amdgcn_s_setprio(0);
        __builtin_amdgcn_s_barrier();      // all waves done reading buf[pbuf]
    }

    long prow = (long)(chunk * 32 + p_) * 512 + qb0 + w * 16;
#pragma unroll
    for (int nt = 0; nt < 4; nt++)
        *(f32x4*)&Op[(prow + c) * 64 + nt * 16 + g * 4] = o[nt];
    if (g == 0) ML[prow + c] = make_float2(mrun, lrun);
}

// ---------------- combine: merge 4 kv-chunk partials ----------------
__global__ __launch_bounds__(256) void attn_combine(const float* __restrict__ Op,
                                                    const float2* __restrict__ ML,
                                                    u16* __restrict__ O) {
    int tid = threadIdx.x;
    int w = tid >> 6, l = tid & 63;
    long rid = (long)blockIdx.x * 4 + w;   // 0..16383 : (p_, row)
    int p_ = (int)(rid >> 9);
    int row = (int)(rid & 511);
    int b = p_ >> 3, h = p_ & 7;
    float2 m[4];
#pragma unroll
    for (int cc = 0; cc < 4; cc++) m[cc] = ML[((long)(cc * 32 + p_) * 512 + row)];
    float mstar = fmaxf(fmaxf(m[0].x, m[1].x), fmaxf(m[2].x, m[3].x));
    float wsum = 0.f, acc = 0.f;
#pragma unroll
    for (int cc = 0; cc < 4; cc++) {
        float wgt = exp2f(m[cc].x - mstar);
        wsum += wgt * m[cc].y;
        acc += wgt * Op[((long)(cc * 32 + p_) * 512 + row) * 64 + l];
    }
    O[((long)(b * 512 + row)) * 512 + h * 64 + l] = f2bf(acc / wsum);
}

// ---------------- launch ----------------

extern "C" void kernel_launch(void* const* d_in, const int* in_sizes, int n_in,
                              void* d_out, int out_size, void* d_ws, size_t ws_size,
                              hipStream_t stream) {
    const float* x = (const float*)d_in[0];
    const float* ctx = (const float*)d_in[1];
    const float* Wq = (const float*)d_in[2];
    const float* Wkv = (const float*)d_in[3];
    const float* Wout = (const float*)d_in[4];
    float* out = (float*)d_out;

    char* ws = (char*)d_ws;
    size_t off = 0;
    auto alloc = [&](size_t bytes) {
        size_t r = off;
        off += (bytes + 255) & ~(size_t)255;
        return r;
    };
    u16* ctxb = (u16*)(ws + alloc(4L * 4608 * 512 * 2));
    u16* wqb = (u16*)(ws + alloc(512L * 512 * 2));
    u16* wkvb = (u16*)(ws + alloc(1024L * 512 * 2));
    u16* woutb = (u16*)(ws + alloc(512L * 512 * 2));
    u16* qb = (u16*)(ws + alloc(2048L * 512 * 2));
    u16* kb = (u16*)(ws + alloc(4L * 4608 * 512 * 2));
    u16* vtb = (u16*)(ws + alloc(4L * 8 * 64 * 4608 * 2));
    u16* aob = (u16*)(ws + alloc(2048L * 512 * 2));
    float* opb = (float*)(ws + alloc(4L * 32 * 512 * 64 * 4));   // 16.8 MB
    float2* mlb = (float2*)(ws + alloc(4L * 32 * 512 * 8));      // 0.5 MB

    prep_all<<<dim3(5120), dim3(256), 0, stream>>>(x, ctx, Wq, Wkv, Wout,
                                                   ctxb, wqb, wkvb, woutb);
    // kv projection (rows 0..143) + q projection (rows 144..159, bx<2)
    gemm_kvq<<<dim3(4, 160), dim3(512), 0, stream>>>(ctxb, wkvb, wqb, kb, vtb, qb);
    attn_kern<<<dim3(1024), dim3(256), 0, stream>>>(qb, kb, vtb, opb, mlb);
    attn_combine<<<dim3(4096), dim3(256), 0, stream>>>(opb, mlb, aob);
    gemm_out<<<dim3(4, 16), dim3(256), 0, stream>>>(aob, woutb, out);
}